// Round 3
// baseline (328.731 us; speedup 1.0000x reference)
//
#include <hip/hip_runtime.h>
#include <hip/hip_bf16.h>
#include <cstdint>

#define B_   2
#define T_   2048
#define C_   1024
#define NH_  16
#define HS_  64
#define WIN_ 256
#define M_   (B_*T_)   // 4096

typedef __attribute__((ext_vector_type(8)))  short          short8;
typedef __attribute__((ext_vector_type(8)))  unsigned short ushortx8;
typedef __attribute__((ext_vector_type(8)))  __bf16         bf16x8;
typedef __attribute__((ext_vector_type(4)))  float          floatx4;
typedef __attribute__((ext_vector_type(16))) float          floatx16;

__device__ __forceinline__ unsigned short f2bf(float f) {
    union { float f; uint32_t u; } v; v.f = f;
    uint32_t r = (v.u + 0x7FFFu + ((v.u >> 16) & 1u)) >> 16;
    return (unsigned short)r;
}

__device__ __forceinline__ floatx4 mfma16(short8 a, short8 b, floatx4 c) {
    return __builtin_amdgcn_mfma_f32_16x16x32_bf16(
        __builtin_bit_cast(bf16x8, a), __builtin_bit_cast(bf16x8, b), c, 0, 0, 0);
}
__device__ __forceinline__ floatx16 mfma32(short8 a, short8 b, floatx16 c) {
    return __builtin_amdgcn_mfma_f32_32x32x16_bf16(
        __builtin_bit_cast(bf16x8, a), __builtin_bit_cast(bf16x8, b), c, 0, 0, 0);
}

__device__ __forceinline__ void async16(const void* g, void* l) {
    __builtin_amdgcn_global_load_lds(
        (const __attribute__((address_space(1))) void*)g,
        (__attribute__((address_space(3))) void*)l, 16, 0, 0);
}

// ---------------------------------------------------------------------------
// Fused prep (x convert + both weight transposes)
// ---------------------------------------------------------------------------
#define NB_CONV 4096
#define NB_WA   768
#define NB_WP   256

__device__ void transpose_tile(const float* __restrict__ in, unsigned short* __restrict__ out,
                               int K, int N, int kt, int nt, unsigned short (*tile)[65])
{
    const int k0 = kt * 64, n0 = nt * 64;
    const int tr = threadIdx.x >> 4;
    const int tc = (threadIdx.x & 15) * 4;
    #pragma unroll
    for (int it = 0; it < 4; it++) {
        int row = tr + it * 16;
        float4 v = *(const float4*)&in[(size_t)(k0 + row) * N + n0 + tc];
        tile[row][tc + 0] = f2bf(v.x);
        tile[row][tc + 1] = f2bf(v.y);
        tile[row][tc + 2] = f2bf(v.z);
        tile[row][tc + 3] = f2bf(v.w);
    }
    __syncthreads();
    #pragma unroll
    for (int it = 0; it < 4; it++) {
        int nrow = tr + it * 16;
        ushort4 h;
        h.x = tile[tc + 0][nrow]; h.y = tile[tc + 1][nrow];
        h.z = tile[tc + 2][nrow]; h.w = tile[tc + 3][nrow];
        *(ushort4*)&out[(size_t)(n0 + nrow) * K + k0 + tc] = h;
    }
}

__global__ __launch_bounds__(256)
void prep_kernel(const float* __restrict__ x, const float* __restrict__ W_attn,
                 const float* __restrict__ W_proj,
                 unsigned short* __restrict__ xb, unsigned short* __restrict__ Wa_t,
                 unsigned short* __restrict__ Wp_t)
{
    __shared__ unsigned short tile[64][65];
    const int bid = blockIdx.x;
    if (bid < NB_CONV) {
        int i = (bid * 256 + threadIdx.x) * 4;
        float4 v = *(const float4*)&x[i];
        ushort4 h;
        h.x = f2bf(v.x); h.y = f2bf(v.y); h.z = f2bf(v.z); h.w = f2bf(v.w);
        *(ushort4*)&xb[i] = h;
    } else if (bid < NB_CONV + NB_WA) {
        int idx = bid - NB_CONV;
        transpose_tile(W_attn, Wa_t, C_, 3 * C_, idx / 48, idx % 48, tile);
    } else {
        int idx = bid - NB_CONV - NB_WA;
        transpose_tile(W_proj, Wp_t, C_, C_, idx / 16, idx % 16, tile);
    }
}

// ---------------------------------------------------------------------------
// GEMM, 32x32x16 MFMA, BK=64, XOR-swizzled LDS — Round-0 structure.
// REP: diagnostic repeat (idempotent re-computation) to surface this
// dispatch above the 42-us harness fills in rocprof's top-5.
// ---------------------------------------------------------------------------
template<int MT, bool OUT_BF16, bool VSPLIT, int REP>
__global__ __launch_bounds__(256)
void gemm32(const unsigned short* __restrict__ A,
            const unsigned short* __restrict__ Bt,
            void* __restrict__ Cp, unsigned short* __restrict__ vt,
            int M, int N, int K)
{
    constexpr int BK = 64;
    constexpr int BM = 64 * MT;
    __shared__ unsigned short As[BM * BK];
    __shared__ unsigned short Bs[128 * BK];

    const int tid  = threadIdx.x;
    const int lane = tid & 63;
    const int wave = tid >> 6;
    const int l32  = lane & 31;
    const int hi   = lane >> 5;
    const int px   = l32 & 7;
    const int wm   = (wave & 1) * 32 * MT;
    const int wn   = (wave >> 1) * 64;
    const int m0   = blockIdx.y * BM;
    const int n0   = blockIdx.x * 128;

    const int ri = lane >> 3;
    const int pg = lane & 7;
    const int gg = pg ^ ri;

    const unsigned short* gA = &A[(size_t)(m0 + wave * 8 + ri) * K + gg * 8];
    const unsigned short* gB = &Bt[(size_t)(n0 + wave * 8 + ri) * K + gg * 8];
    unsigned short* lA = &As[(wave * 8) * BK];
    unsigned short* lB = &Bs[(wave * 8) * BK];

    #pragma unroll 1
    for (int rep = 0; rep < REP; rep++) {

    floatx16 acc[MT][2];
    #pragma unroll
    for (int i = 0; i < MT; i++)
        #pragma unroll
        for (int j = 0; j < 2; j++) acc[i][j] = (floatx16)(0.f);

    for (int k0 = 0; k0 < K; k0 += BK) {
        #pragma unroll
        for (int s = 0; s < 2 * MT; s++)
            async16(gA + k0 + (size_t)s * 32 * K, lA + s * 32 * BK);
        #pragma unroll
        for (int s = 0; s < 4; s++)
            async16(gB + k0 + (size_t)s * 32 * K, lB + s * 32 * BK);
        __syncthreads();

        #pragma unroll
        for (int ks = 0; ks < 4; ks++) {
            short8 af[MT], bfr[2];
            #pragma unroll
            for (int i = 0; i < MT; i++) {
                int r = wm + i * 32 + l32;
                int p = (ks * 2 + hi) ^ px;
                af[i] = *(const short8*)(&As[r * BK + p * 8]);
            }
            #pragma unroll
            for (int j = 0; j < 2; j++) {
                int r = wn + j * 32 + l32;
                int p = (ks * 2 + hi) ^ px;
                bfr[j] = *(const short8*)(&Bs[r * BK + p * 8]);
            }
            #pragma unroll
            for (int i = 0; i < MT; i++)
                #pragma unroll
                for (int j = 0; j < 2; j++)
                    acc[i][j] = mfma32(af[i], bfr[j], acc[i][j]);
        }
        __syncthreads();
    }

    #pragma unroll
    for (int i = 0; i < MT; i++)
        #pragma unroll
        for (int j = 0; j < 2; j++) {
            const int col  = n0 + wn + j * 32 + l32;
            const int row0 = m0 + wm + i * 32 + 4 * hi;
            if (VSPLIT && col >= 2 * C_) {
                const int hd = col - 2 * C_;
                const int hh = hd >> 6, d = hd & 63;
                #pragma unroll
                for (int g = 0; g < 4; g++) {
                    int rowg = row0 + 8 * g;
                    int bb = rowg >> 11, t = rowg & (T_ - 1);
                    ushort4 h4;
                    h4.x = f2bf(acc[i][j][g * 4 + 0]);
                    h4.y = f2bf(acc[i][j][g * 4 + 1]);
                    h4.z = f2bf(acc[i][j][g * 4 + 2]);
                    h4.w = f2bf(acc[i][j][g * 4 + 3]);
                    *(ushort4*)&vt[((size_t)(bb * NH_ + hh) * 64 + d) * T_ + t] = h4;
                }
            } else {
                #pragma unroll
                for (int g = 0; g < 4; g++)
                    #pragma unroll
                    for (int rr = 0; rr < 4; rr++) {
                        int row = row0 + 8 * g + rr;
                        if (OUT_BF16)
                            ((unsigned short*)Cp)[(size_t)row * N + col] = f2bf(acc[i][j][g * 4 + rr]);
                        else
                            ((float*)Cp)[(size_t)row * N + col] = acc[i][j][g * 4 + rr];
                    }
            }
        }

    }   // rep
}

// ---------------------------------------------------------------------------
// Sliding-window attention: Round-0 version. REP diagnostic repeat.
// ---------------------------------------------------------------------------
template<int REP>
__global__ __launch_bounds__(256)
void attn_kernel(const unsigned short* __restrict__ qkv,
                 const unsigned short* __restrict__ vt,
                 unsigned short* __restrict__ y)
{
    __shared__ unsigned short Ks[64 * 64];      // [key][d] swizzled
    __shared__ unsigned short Vs[64 * 64];      // [d][key] swizzled
    __shared__ unsigned short Ps[4][16 * 72];   // per-wave P strip

    const int tid  = threadIdx.x;
    const int lane = tid & 63;
    const int wave = tid >> 6;
    const int l16  = lane & 15;
    const int quad = lane >> 4;
    const int sw   = l16 & 7;                   // fragment swizzle key

    // XCD-aware decode of flat 1024-block grid
    const int g  = blockIdx.x;
    const int yq = g >> 3;
    const int hb = (g & 7) + 8 * (yq >> 5);
    const int qt = yq & 31;
    const int h  = hb & 15;
    const int b  = hb >> 4;

    const int q0b = qt * 64;            // block q-tile base
    const int q0w = q0b + wave * 16;    // this wave's q-base
    const size_t base = (size_t)b * T_;
    const int ROW  = 3 * C_;
    const int qoff = h * HS_;
    const int koff = C_ + h * HS_;
    const size_t vbase = ((size_t)(b * NH_ + h) * 64) * T_;
    unsigned short* Pstrip = Ps[wave];
    const float SC = 0.125f * 1.44269504f;

    // DMA lane mapping: lane = 8*ri + pg ; global granule gg = pg ^ ri
    const int ri = lane >> 3;
    const int gg = (lane & 7) ^ ri;

    // Q a-frags (once)
    short8 aq[2];
    #pragma unroll
    for (int ks = 0; ks < 2; ks++)
        aq[ks] = *(const short8*)&qkv[(base + q0w + l16) * ROW + qoff + ks * 32 + quad * 8];

    int kb_lo = q0b - (WIN_ - 1);
    kb_lo = (kb_lo > 0 ? kb_lo : 0) & ~63;

    #pragma unroll 1
    for (int rep = 0; rep < REP; rep++) {

    floatx4 O[4];
    #pragma unroll
    for (int j = 0; j < 4; j++) O[j] = (floatx4){0.f, 0.f, 0.f, 0.f};
    float psum[4] = {0.f, 0.f, 0.f, 0.f};

    for (int kb = kb_lo; kb <= q0b; kb += 64) {
        __syncthreads();   // all waves done reading previous tile
        // stage K tile: rows wave*16 + c*8 + ri, 128 B each (coalesced)
        #pragma unroll
        for (int c = 0; c < 2; c++) {
            int row = wave * 16 + c * 8;
            async16(&qkv[(base + kb + row + ri) * ROW + koff + gg * 8],
                    &Ks[row * 64]);
            async16(&vt[vbase + (size_t)(row + ri) * T_ + kb + gg * 8],
                    &Vs[row * 64]);
        }
        __syncthreads();   // vmcnt drain -> tiles ready

        // ---- S = Q K^T ----
        floatx4 s[4];
        #pragma unroll
        for (int nt = 0; nt < 4; nt++) s[nt] = (floatx4){0.f, 0.f, 0.f, 0.f};
        #pragma unroll
        for (int ks = 0; ks < 2; ks++)
            #pragma unroll
            for (int nt = 0; nt < 4; nt++) {
                short8 bk = *(const short8*)&Ks[(nt * 16 + l16) * 64
                                                + (((ks * 4 + quad) ^ sw) * 8)];
                s[nt] = mfma16(aq[ks], bk, s[nt]);
            }

        // ---- mask + exp + psum ----
        #pragma unroll
        for (int nt = 0; nt < 4; nt++)
            #pragma unroll
            for (int r = 0; r < 4; r++) {
                int dist = (q0w + quad * 4 + r) - (kb + nt * 16 + l16);
                float sv = ((unsigned)dist < (unsigned)WIN_) ? s[nt][r] * SC : -1e30f;
                float e = exp2f(sv);
                psum[r] += e;
                s[nt][r] = e;
            }

        // ---- P roundtrip (wave-private) ----
        #pragma unroll
        for (int nt = 0; nt < 4; nt++)
            #pragma unroll
            for (int r = 0; r < 4; r++)
                Pstrip[(quad * 4 + r) * 72 + nt * 16 + l16] = f2bf(s[nt][r]);

        // ---- O += P @ V ----
        #pragma unroll
        for (int ks = 0; ks < 2; ks++) {
            short8 ap = *(const short8*)&Pstrip[l16 * 72 + ks * 32 + quad * 8];
            #pragma unroll
            for (int jt = 0; jt < 4; jt++) {
                short8 bv = *(const short8*)&Vs[(jt * 16 + l16) * 64
                                                + (((ks * 4 + quad) ^ sw) * 8)];
                O[jt] = mfma16(ap, bv, O[jt]);
            }
        }
    }

    // ---- row-sum reduce ----
    #pragma unroll
    for (int r = 0; r < 4; r++) {
        #pragma unroll
        for (int off = 8; off >= 1; off >>= 1)
            psum[r] += __shfl_xor(psum[r], off, 64);
    }

    // ---- epilogue via per-wave strip, coalesced ushort8 writes ----
    #pragma unroll
    for (int jt = 0; jt < 4; jt++)
        #pragma unroll
        for (int r = 0; r < 4; r++)
            Pstrip[(quad * 4 + r) * 72 + jt * 16 + l16] = f2bf(O[jt][r] / psum[r]);
    #pragma unroll
    for (int it = 0; it < 2; it++) {
        int c = lane + 64 * it;
        int qr = c >> 3, dc = (c & 7) * 8;
        *(ushortx8*)&y[(base + q0w + qr) * C_ + qoff + dc] =
            *(const ushortx8*)&Pstrip[qr * 72 + dc];
    }

    }   // rep
}

// ---------------------------------------------------------------------------
extern "C" void kernel_launch(void* const* d_in, const int* in_sizes, int n_in,
                              void* d_out, int out_size, void* d_ws, size_t ws_size,
                              hipStream_t stream)
{
    const float* x      = (const float*)d_in[0];
    const float* W_attn = (const float*)d_in[1];
    const float* W_proj = (const float*)d_in[2];
    float* out = (float*)d_out;

    unsigned short* xb   = (unsigned short*)d_ws;                 // [M][C]      8 MB
    unsigned short* Wa_t = xb   + (size_t)M_ * C_;                // [3C][C]     6 MB
    unsigned short* Wp_t = Wa_t + (size_t)3 * C_ * C_;            // [C][C]      2 MB
    unsigned short* qkv  = Wp_t + (size_t)C_ * C_;                // [M][3C]    24 MB (Q,K)
    unsigned short* y    = qkv  + (size_t)M_ * 3 * C_;            // [M][C]      8 MB
    unsigned short* vtg  = y    + (size_t)M_ * C_;                // [B][NH][64][T] 8 MB

    dim3 blk(256);
    prep_kernel<<<NB_CONV + NB_WA + NB_WP, blk, 0, stream>>>(x, W_attn, W_proj, xb, Wa_t, Wp_t);
    // QKV GEMM: Round-0 structure, rep=2 (diagnostic: surfaces counters)
    gemm32<2, true, true, 2><<<dim3((3 * C_) / 128, M_ / 128), blk, 0, stream>>>(
        xb, Wa_t, qkv, vtg, M_, 3 * C_, C_);
    // attn: Round-0 structure, rep=5 (diagnostic)
    attn_kernel<5><<<(T_ / 64) * NH_ * B_, blk, 0, stream>>>(qkv, vtg, y);
    // proj GEMM: MT=2 hypothesis (128x128 tile, halves staged bytes/FLOP), rep=5
    gemm32<2, false, false, 5><<<dim3(C_ / 128, M_ / 128), blk, 0, stream>>>(
        y, Wp_t, out, nullptr, M_, C_, C_);
}

// Round 4
// 162.716 us; speedup vs baseline: 2.0203x; 2.0203x over previous
//
#include <hip/hip_runtime.h>
#include <hip/hip_bf16.h>
#include <cstdint>

#define B_   2
#define T_   2048
#define C_   1024
#define NH_  16
#define HS_  64
#define WIN_ 256
#define M_   (B_*T_)   // 4096

typedef __attribute__((ext_vector_type(8)))  short          short8;
typedef __attribute__((ext_vector_type(8)))  unsigned short ushortx8;
typedef __attribute__((ext_vector_type(8)))  __bf16         bf16x8;
typedef __attribute__((ext_vector_type(4)))  float          floatx4;
typedef __attribute__((ext_vector_type(16))) float          floatx16;

__device__ __forceinline__ unsigned short f2bf(float f) {
    union { float f; uint32_t u; } v; v.f = f;
    uint32_t r = (v.u + 0x7FFFu + ((v.u >> 16) & 1u)) >> 16;
    return (unsigned short)r;
}

__device__ __forceinline__ floatx4 mfma16(short8 a, short8 b, floatx4 c) {
    return __builtin_amdgcn_mfma_f32_16x16x32_bf16(
        __builtin_bit_cast(bf16x8, a), __builtin_bit_cast(bf16x8, b), c, 0, 0, 0);
}
__device__ __forceinline__ floatx16 mfma32(short8 a, short8 b, floatx16 c) {
    return __builtin_amdgcn_mfma_f32_32x32x16_bf16(
        __builtin_bit_cast(bf16x8, a), __builtin_bit_cast(bf16x8, b), c, 0, 0, 0);
}

__device__ __forceinline__ void async16(const void* g, void* l) {
    __builtin_amdgcn_global_load_lds(
        (const __attribute__((address_space(1))) void*)g,
        (__attribute__((address_space(3))) void*)l, 16, 0, 0);
}

// ---------------------------------------------------------------------------
// Fused prep (x convert + both weight transposes)
// ---------------------------------------------------------------------------
#define NB_CONV 4096
#define NB_WA   768
#define NB_WP   256

__device__ void transpose_tile(const float* __restrict__ in, unsigned short* __restrict__ out,
                               int K, int N, int kt, int nt, unsigned short (*tile)[65])
{
    const int k0 = kt * 64, n0 = nt * 64;
    const int tr = threadIdx.x >> 4;
    const int tc = (threadIdx.x & 15) * 4;
    #pragma unroll
    for (int it = 0; it < 4; it++) {
        int row = tr + it * 16;
        float4 v = *(const float4*)&in[(size_t)(k0 + row) * N + n0 + tc];
        tile[row][tc + 0] = f2bf(v.x);
        tile[row][tc + 1] = f2bf(v.y);
        tile[row][tc + 2] = f2bf(v.z);
        tile[row][tc + 3] = f2bf(v.w);
    }
    __syncthreads();
    #pragma unroll
    for (int it = 0; it < 4; it++) {
        int nrow = tr + it * 16;
        ushort4 h;
        h.x = tile[tc + 0][nrow]; h.y = tile[tc + 1][nrow];
        h.z = tile[tc + 2][nrow]; h.w = tile[tc + 3][nrow];
        *(ushort4*)&out[(size_t)(n0 + nrow) * K + k0 + tc] = h;
    }
}

__global__ __launch_bounds__(256)
void prep_kernel(const float* __restrict__ x, const float* __restrict__ W_attn,
                 const float* __restrict__ W_proj,
                 unsigned short* __restrict__ xb, unsigned short* __restrict__ Wa_t,
                 unsigned short* __restrict__ Wp_t)
{
    __shared__ unsigned short tile[64][65];
    const int bid = blockIdx.x;
    if (bid < NB_CONV) {
        int i = (bid * 256 + threadIdx.x) * 4;
        float4 v = *(const float4*)&x[i];
        ushort4 h;
        h.x = f2bf(v.x); h.y = f2bf(v.y); h.z = f2bf(v.z); h.w = f2bf(v.w);
        *(ushort4*)&xb[i] = h;
    } else if (bid < NB_CONV + NB_WA) {
        int idx = bid - NB_CONV;
        transpose_tile(W_attn, Wa_t, C_, 3 * C_, idx / 48, idx % 48, tile);
    } else {
        int idx = bid - NB_CONV - NB_WA;
        transpose_tile(W_proj, Wp_t, C_, C_, idx / 16, idx % 16, tile);
    }
}

// ---------------------------------------------------------------------------
// GEMM, 32x32x16 MFMA, 128x128 tile, BK=64, XOR-swizzled LDS,
// T3 minimum-2-phase: double-buffered LDS, stage(t+1) issued BEFORE tile t's
// compute, counted s_waitcnt vmcnt(8) (only the prefetch's 8 loads/thread may
// remain in flight) + raw s_barrier pair per K-tile. Race-safe: buf[(t+1)&1]
// was last read in tile t-1 whose end-barrier precedes the stage issue.
// ---------------------------------------------------------------------------
template<int MT, bool OUT_BF16, bool VSPLIT>
__global__ __launch_bounds__(256)
void gemm32db(const unsigned short* __restrict__ A,
              const unsigned short* __restrict__ Bt,
              void* __restrict__ Cp, unsigned short* __restrict__ vt,
              int M, int N, int K)
{
    constexpr int BK = 64;
    constexpr int BM = 64 * MT;
    __shared__ unsigned short As[2][BM * BK];
    __shared__ unsigned short Bs[2][128 * BK];

    const int tid  = threadIdx.x;
    const int lane = tid & 63;
    const int wave = tid >> 6;
    const int l32  = lane & 31;
    const int hi   = lane >> 5;
    const int px   = l32 & 7;
    const int wm   = (wave & 1) * 32 * MT;
    const int wn   = (wave >> 1) * 64;
    const int m0   = blockIdx.y * BM;
    const int n0   = blockIdx.x * 128;

    const int ri = lane >> 3;
    const int pg = lane & 7;
    const int gg = pg ^ ri;

    floatx16 acc[MT][2];
    #pragma unroll
    for (int i = 0; i < MT; i++)
        #pragma unroll
        for (int j = 0; j < 2; j++) acc[i][j] = (floatx16)(0.f);

    const unsigned short* gA = &A[(size_t)(m0 + wave * 8 + ri) * K + gg * 8];
    const unsigned short* gB = &Bt[(size_t)(n0 + wave * 8 + ri) * K + gg * 8];

    // stage K-tile at element offset k0 into buffer buf (8 loads/thread)
    auto stage = [&](int buf, int k0) {
        #pragma unroll
        for (int s = 0; s < 2 * MT; s++)
            async16(gA + k0 + (size_t)s * 32 * K, &As[buf][(wave * 8 + s * 32) * BK]);
        #pragma unroll
        for (int s = 0; s < 4; s++)
            async16(gB + k0 + (size_t)s * 32 * K, &Bs[buf][(wave * 8 + s * 32) * BK]);
    };

    const int NT = K / BK;
    stage(0, 0);
    asm volatile("s_waitcnt vmcnt(0)" ::: "memory");
    __builtin_amdgcn_s_barrier();

    for (int t = 0; t < NT; t++) {
        const int cur = t & 1;
        if (t + 1 < NT) {
            stage(cur ^ 1, (t + 1) * BK);            // prefetch next tile
            asm volatile("s_waitcnt vmcnt(8)" ::: "memory");  // tile t landed (mine)
        } else {
            asm volatile("s_waitcnt vmcnt(0)" ::: "memory");
        }
        __builtin_amdgcn_s_barrier();                // tile t landed (everyone)
        __builtin_amdgcn_sched_barrier(0);

        const unsigned short* cA = As[cur];
        const unsigned short* cB = Bs[cur];
        #pragma unroll
        for (int ks = 0; ks < 4; ks++) {
            const int p = ((ks * 2 + hi) ^ px) * 8;
            short8 af[MT], bfr[2];
            #pragma unroll
            for (int i = 0; i < MT; i++)
                af[i] = *(const short8*)(&cA[(wm + i * 32 + l32) * BK + p]);
            #pragma unroll
            for (int j = 0; j < 2; j++)
                bfr[j] = *(const short8*)(&cB[(wn + j * 32 + l32) * BK + p]);
            #pragma unroll
            for (int i = 0; i < MT; i++)
                #pragma unroll
                for (int j = 0; j < 2; j++)
                    acc[i][j] = mfma32(af[i], bfr[j], acc[i][j]);
        }
        asm volatile("" ::: "memory");
        __builtin_amdgcn_s_barrier();                // all done reading buf[cur]
    }

    #pragma unroll
    for (int i = 0; i < MT; i++)
        #pragma unroll
        for (int j = 0; j < 2; j++) {
            const int col  = n0 + wn + j * 32 + l32;
            const int row0 = m0 + wm + i * 32 + 4 * hi;
            if (VSPLIT && col >= 2 * C_) {
                const int hd = col - 2 * C_;
                const int hh = hd >> 6, d = hd & 63;
                #pragma unroll
                for (int g = 0; g < 4; g++) {
                    int rowg = row0 + 8 * g;
                    int bb = rowg >> 11, t = rowg & (T_ - 1);
                    ushort4 h4;
                    h4.x = f2bf(acc[i][j][g * 4 + 0]);
                    h4.y = f2bf(acc[i][j][g * 4 + 1]);
                    h4.z = f2bf(acc[i][j][g * 4 + 2]);
                    h4.w = f2bf(acc[i][j][g * 4 + 3]);
                    *(ushort4*)&vt[((size_t)(bb * NH_ + hh) * 64 + d) * T_ + t] = h4;
                }
            } else {
                #pragma unroll
                for (int g = 0; g < 4; g++)
                    #pragma unroll
                    for (int rr = 0; rr < 4; rr++) {
                        int row = row0 + 8 * g + rr;
                        if (OUT_BF16)
                            ((unsigned short*)Cp)[(size_t)row * N + col] = f2bf(acc[i][j][g * 4 + rr]);
                        else
                            ((float*)Cp)[(size_t)row * N + col] = acc[i][j][g * 4 + rr];
                    }
            }
        }
}

// ---------------------------------------------------------------------------
// Sliding-window attention: Round-0 version, bit-identical (single-buffered
// K/V staging, __syncthreads drain; 25.2 KB LDS -> 6 blocks/CU).
// ---------------------------------------------------------------------------
__global__ __launch_bounds__(256)
void attn_kernel(const unsigned short* __restrict__ qkv,
                 const unsigned short* __restrict__ vt,
                 unsigned short* __restrict__ y)
{
    __shared__ unsigned short Ks[64 * 64];      // [key][d] swizzled
    __shared__ unsigned short Vs[64 * 64];      // [d][key] swizzled
    __shared__ unsigned short Ps[4][16 * 72];   // per-wave P strip

    const int tid  = threadIdx.x;
    const int lane = tid & 63;
    const int wave = tid >> 6;
    const int l16  = lane & 15;
    const int quad = lane >> 4;
    const int sw   = l16 & 7;                   // fragment swizzle key

    // XCD-aware decode of flat 1024-block grid
    const int g  = blockIdx.x;
    const int yq = g >> 3;
    const int hb = (g & 7) + 8 * (yq >> 5);
    const int qt = yq & 31;
    const int h  = hb & 15;
    const int b  = hb >> 4;

    const int q0b = qt * 64;            // block q-tile base
    const int q0w = q0b + wave * 16;    // this wave's q-base
    const size_t base = (size_t)b * T_;
    const int ROW  = 3 * C_;
    const int qoff = h * HS_;
    const int koff = C_ + h * HS_;
    const size_t vbase = ((size_t)(b * NH_ + h) * 64) * T_;
    unsigned short* Pstrip = Ps[wave];
    const float SC = 0.125f * 1.44269504f;

    // DMA lane mapping: lane = 8*ri + pg ; global granule gg = pg ^ ri
    const int ri = lane >> 3;
    const int gg = (lane & 7) ^ ri;

    // Q a-frags (once)
    short8 aq[2];
    #pragma unroll
    for (int ks = 0; ks < 2; ks++)
        aq[ks] = *(const short8*)&qkv[(base + q0w + l16) * ROW + qoff + ks * 32 + quad * 8];

    floatx4 O[4];
    #pragma unroll
    for (int j = 0; j < 4; j++) O[j] = (floatx4){0.f, 0.f, 0.f, 0.f};
    float psum[4] = {0.f, 0.f, 0.f, 0.f};

    int kb_lo = q0b - (WIN_ - 1);
    kb_lo = (kb_lo > 0 ? kb_lo : 0) & ~63;

    for (int kb = kb_lo; kb <= q0b; kb += 64) {
        __syncthreads();   // all waves done reading previous tile
        // stage K tile: rows wave*16 + c*8 + ri, 128 B each (coalesced)
        #pragma unroll
        for (int c = 0; c < 2; c++) {
            int row = wave * 16 + c * 8;
            async16(&qkv[(base + kb + row + ri) * ROW + koff + gg * 8],
                    &Ks[row * 64]);
            async16(&vt[vbase + (size_t)(row + ri) * T_ + kb + gg * 8],
                    &Vs[row * 64]);
        }
        __syncthreads();   // vmcnt drain -> tiles ready

        // ---- S = Q K^T ----
        floatx4 s[4];
        #pragma unroll
        for (int nt = 0; nt < 4; nt++) s[nt] = (floatx4){0.f, 0.f, 0.f, 0.f};
        #pragma unroll
        for (int ks = 0; ks < 2; ks++)
            #pragma unroll
            for (int nt = 0; nt < 4; nt++) {
                short8 bk = *(const short8*)&Ks[(nt * 16 + l16) * 64
                                                + (((ks * 4 + quad) ^ sw) * 8)];
                s[nt] = mfma16(aq[ks], bk, s[nt]);
            }

        // ---- mask + exp + psum ----
        #pragma unroll
        for (int nt = 0; nt < 4; nt++)
            #pragma unroll
            for (int r = 0; r < 4; r++) {
                int dist = (q0w + quad * 4 + r) - (kb + nt * 16 + l16);
                float sv = ((unsigned)dist < (unsigned)WIN_) ? s[nt][r] * SC : -1e30f;
                float e = exp2f(sv);
                psum[r] += e;
                s[nt][r] = e;
            }

        // ---- P roundtrip (wave-private) ----
        #pragma unroll
        for (int nt = 0; nt < 4; nt++)
            #pragma unroll
            for (int r = 0; r < 4; r++)
                Pstrip[(quad * 4 + r) * 72 + nt * 16 + l16] = f2bf(s[nt][r]);

        // ---- O += P @ V ----
        #pragma unroll
        for (int ks = 0; ks < 2; ks++) {
            short8 ap = *(const short8*)&Pstrip[l16 * 72 + ks * 32 + quad * 8];
            #pragma unroll
            for (int jt = 0; jt < 4; jt++) {
                short8 bv = *(const short8*)&Vs[(jt * 16 + l16) * 64
                                                + (((ks * 4 + quad) ^ sw) * 8)];
                O[jt] = mfma16(ap, bv, O[jt]);
            }
        }
    }

    // ---- row-sum reduce ----
    #pragma unroll
    for (int r = 0; r < 4; r++) {
        #pragma unroll
        for (int off = 8; off >= 1; off >>= 1)
            psum[r] += __shfl_xor(psum[r], off, 64);
    }

    // ---- epilogue via per-wave strip, coalesced ushort8 writes ----
    #pragma unroll
    for (int jt = 0; jt < 4; jt++)
        #pragma unroll
        for (int r = 0; r < 4; r++)
            Pstrip[(quad * 4 + r) * 72 + jt * 16 + l16] = f2bf(O[jt][r] / psum[r]);
    #pragma unroll
    for (int it = 0; it < 2; it++) {
        int c = lane + 64 * it;
        int qr = c >> 3, dc = (c & 7) * 8;
        *(ushortx8*)&y[(base + q0w + qr) * C_ + qoff + dc] =
            *(const ushortx8*)&Pstrip[qr * 72 + dc];
    }
}

// ---------------------------------------------------------------------------
extern "C" void kernel_launch(void* const* d_in, const int* in_sizes, int n_in,
                              void* d_out, int out_size, void* d_ws, size_t ws_size,
                              hipStream_t stream)
{
    const float* x      = (const float*)d_in[0];
    const float* W_attn = (const float*)d_in[1];
    const float* W_proj = (const float*)d_in[2];
    float* out = (float*)d_out;

    unsigned short* xb   = (unsigned short*)d_ws;                 // [M][C]      8 MB
    unsigned short* Wa_t = xb   + (size_t)M_ * C_;                // [3C][C]     6 MB
    unsigned short* Wp_t = Wa_t + (size_t)3 * C_ * C_;            // [C][C]      2 MB
    unsigned short* qkv  = Wp_t + (size_t)C_ * C_;                // [M][3C]    24 MB (Q,K)
    unsigned short* y    = qkv  + (size_t)M_ * 3 * C_;            // [M][C]      8 MB
    unsigned short* vtg  = y    + (size_t)M_ * C_;                // [B][NH][64][T] 8 MB

    dim3 blk(256);
    prep_kernel<<<NB_CONV + NB_WA + NB_WP, blk, 0, stream>>>(x, W_attn, W_proj, xb, Wa_t, Wp_t);
    // QKV GEMM: 128x128 tile, double-buffered + counted vmcnt (T3 2-phase)
    gemm32db<2, true, true><<<dim3((3 * C_) / 128, M_ / 128), blk, 0, stream>>>(
        xb, Wa_t, qkv, vtg, M_, 3 * C_, C_);
    attn_kernel<<<(T_ / 64) * NH_ * B_, blk, 0, stream>>>(qkv, vtg, y);
    // proj GEMM: MT=2 (validated -10us) + dbuf/counted-vmcnt (grid-limited to
    // 1 block/CU, so the 64 KB LDS costs nothing and prefetch is pure upside)
    gemm32db<2, false, false><<<dim3(C_ / 128, M_ / 128), blk, 0, stream>>>(
        y, Wp_t, out, nullptr, M_, C_, C_);
}

// Round 5
// 160.088 us; speedup vs baseline: 2.0534x; 1.0164x over previous
//
#include <hip/hip_runtime.h>
#include <hip/hip_bf16.h>
#include <cstdint>

#define B_   2
#define T_   2048
#define C_   1024
#define NH_  16
#define HS_  64
#define WIN_ 256
#define M_   (B_*T_)   // 4096

typedef __attribute__((ext_vector_type(8)))  short          short8;
typedef __attribute__((ext_vector_type(8)))  unsigned short ushortx8;
typedef __attribute__((ext_vector_type(8)))  __bf16         bf16x8;
typedef __attribute__((ext_vector_type(4)))  float          floatx4;
typedef __attribute__((ext_vector_type(16))) float          floatx16;

__device__ __forceinline__ unsigned short f2bf(float f) {
    union { float f; uint32_t u; } v; v.f = f;
    uint32_t r = (v.u + 0x7FFFu + ((v.u >> 16) & 1u)) >> 16;
    return (unsigned short)r;
}

__device__ __forceinline__ floatx4 mfma16(short8 a, short8 b, floatx4 c) {
    return __builtin_amdgcn_mfma_f32_16x16x32_bf16(
        __builtin_bit_cast(bf16x8, a), __builtin_bit_cast(bf16x8, b), c, 0, 0, 0);
}
__device__ __forceinline__ floatx16 mfma32(short8 a, short8 b, floatx16 c) {
    return __builtin_amdgcn_mfma_f32_32x32x16_bf16(
        __builtin_bit_cast(bf16x8, a), __builtin_bit_cast(bf16x8, b), c, 0, 0, 0);
}

__device__ __forceinline__ void async16(const void* g, void* l) {
    __builtin_amdgcn_global_load_lds(
        (const __attribute__((address_space(1))) void*)g,
        (__attribute__((address_space(3))) void*)l, 16, 0, 0);
}

// ---------------------------------------------------------------------------
// Fused prep (x convert + both weight transposes) — Round-0 exact
// ---------------------------------------------------------------------------
#define NB_CONV 4096
#define NB_WA   768
#define NB_WP   256

__device__ void transpose_tile(const float* __restrict__ in, unsigned short* __restrict__ out,
                               int K, int N, int kt, int nt, unsigned short (*tile)[65])
{
    const int k0 = kt * 64, n0 = nt * 64;
    const int tr = threadIdx.x >> 4;
    const int tc = (threadIdx.x & 15) * 4;
    #pragma unroll
    for (int it = 0; it < 4; it++) {
        int row = tr + it * 16;
        float4 v = *(const float4*)&in[(size_t)(k0 + row) * N + n0 + tc];
        tile[row][tc + 0] = f2bf(v.x);
        tile[row][tc + 1] = f2bf(v.y);
        tile[row][tc + 2] = f2bf(v.z);
        tile[row][tc + 3] = f2bf(v.w);
    }
    __syncthreads();
    #pragma unroll
    for (int it = 0; it < 4; it++) {
        int nrow = tr + it * 16;
        ushort4 h;
        h.x = tile[tc + 0][nrow]; h.y = tile[tc + 1][nrow];
        h.z = tile[tc + 2][nrow]; h.w = tile[tc + 3][nrow];
        *(ushort4*)&out[(size_t)(n0 + nrow) * K + k0 + tc] = h;
    }
}

__global__ __launch_bounds__(256)
void prep_kernel(const float* __restrict__ x, const float* __restrict__ W_attn,
                 const float* __restrict__ W_proj,
                 unsigned short* __restrict__ xb, unsigned short* __restrict__ Wa_t,
                 unsigned short* __restrict__ Wp_t)
{
    __shared__ unsigned short tile[64][65];
    const int bid = blockIdx.x;
    if (bid < NB_CONV) {
        int i = (bid * 256 + threadIdx.x) * 4;
        float4 v = *(const float4*)&x[i];
        ushort4 h;
        h.x = f2bf(v.x); h.y = f2bf(v.y); h.z = f2bf(v.z); h.w = f2bf(v.w);
        *(ushort4*)&xb[i] = h;
    } else if (bid < NB_CONV + NB_WA) {
        int idx = bid - NB_CONV;
        transpose_tile(W_attn, Wa_t, C_, 3 * C_, idx / 48, idx % 48, tile);
    } else {
        int idx = bid - NB_CONV - NB_WA;
        transpose_tile(W_proj, Wp_t, C_, C_, idx / 16, idx % 16, tile);
    }
}

// ---------------------------------------------------------------------------
// GEMM, 32x32x16 MFMA, BK=64, XOR-swizzled LDS — Round-0 structure exact
// (single-buffered; __syncthreads drain; multi-block TLP provides the cover:
// measured 45 us for QKV (3 blk/CU) and 19.7 us for proj at MT=2 (R3 rep=5)).
// Double-buffer + counted-vmcnt variants measured NULL (QKV, R4) and
// -12..-22 us REGRESSION (proj, R4: prefetch DMA LDS-writes contend with
// compute-phase ds_reads on the single per-CU LDS port at 1 blk/CU).
// ---------------------------------------------------------------------------
template<int MT, bool OUT_BF16, bool VSPLIT>
__global__ __launch_bounds__(256)
void gemm32(const unsigned short* __restrict__ A,
            const unsigned short* __restrict__ Bt,
            void* __restrict__ Cp, unsigned short* __restrict__ vt,
            int M, int N, int K)
{
    constexpr int BK = 64;
    constexpr int BM = 64 * MT;
    __shared__ unsigned short As[BM * BK];
    __shared__ unsigned short Bs[128 * BK];

    const int tid  = threadIdx.x;
    const int lane = tid & 63;
    const int wave = tid >> 6;
    const int l32  = lane & 31;
    const int hi   = lane >> 5;
    const int px   = l32 & 7;
    const int wm   = (wave & 1) * 32 * MT;
    const int wn   = (wave >> 1) * 64;
    const int m0   = blockIdx.y * BM;
    const int n0   = blockIdx.x * 128;

    const int ri = lane >> 3;
    const int pg = lane & 7;
    const int gg = pg ^ ri;

    floatx16 acc[MT][2];
    #pragma unroll
    for (int i = 0; i < MT; i++)
        #pragma unroll
        for (int j = 0; j < 2; j++) acc[i][j] = (floatx16)(0.f);

    const unsigned short* gA = &A[(size_t)(m0 + wave * 8 + ri) * K + gg * 8];
    const unsigned short* gB = &Bt[(size_t)(n0 + wave * 8 + ri) * K + gg * 8];
    unsigned short* lA = &As[(wave * 8) * BK];
    unsigned short* lB = &Bs[(wave * 8) * BK];

    for (int k0 = 0; k0 < K; k0 += BK) {
        #pragma unroll
        for (int s = 0; s < 2 * MT; s++)
            async16(gA + k0 + (size_t)s * 32 * K, lA + s * 32 * BK);
        #pragma unroll
        for (int s = 0; s < 4; s++)
            async16(gB + k0 + (size_t)s * 32 * K, lB + s * 32 * BK);
        __syncthreads();

        #pragma unroll
        for (int ks = 0; ks < 4; ks++) {
            short8 af[MT], bfr[2];
            #pragma unroll
            for (int i = 0; i < MT; i++) {
                int r = wm + i * 32 + l32;
                int p = (ks * 2 + hi) ^ px;
                af[i] = *(const short8*)(&As[r * BK + p * 8]);
            }
            #pragma unroll
            for (int j = 0; j < 2; j++) {
                int r = wn + j * 32 + l32;
                int p = (ks * 2 + hi) ^ px;
                bfr[j] = *(const short8*)(&Bs[r * BK + p * 8]);
            }
            #pragma unroll
            for (int i = 0; i < MT; i++)
                #pragma unroll
                for (int j = 0; j < 2; j++)
                    acc[i][j] = mfma32(af[i], bfr[j], acc[i][j]);
        }
        __syncthreads();
    }

    #pragma unroll
    for (int i = 0; i < MT; i++)
        #pragma unroll
        for (int j = 0; j < 2; j++) {
            const int col  = n0 + wn + j * 32 + l32;
            const int row0 = m0 + wm + i * 32 + 4 * hi;
            if (VSPLIT && col >= 2 * C_) {
                const int hd = col - 2 * C_;
                const int hh = hd >> 6, d = hd & 63;
                #pragma unroll
                for (int g = 0; g < 4; g++) {
                    int rowg = row0 + 8 * g;
                    int bb = rowg >> 11, t = rowg & (T_ - 1);
                    ushort4 h4;
                    h4.x = f2bf(acc[i][j][g * 4 + 0]);
                    h4.y = f2bf(acc[i][j][g * 4 + 1]);
                    h4.z = f2bf(acc[i][j][g * 4 + 2]);
                    h4.w = f2bf(acc[i][j][g * 4 + 3]);
                    *(ushort4*)&vt[((size_t)(bb * NH_ + hh) * 64 + d) * T_ + t] = h4;
                }
            } else {
                #pragma unroll
                for (int g = 0; g < 4; g++)
                    #pragma unroll
                    for (int rr = 0; rr < 4; rr++) {
                        int row = row0 + 8 * g + rr;
                        if (OUT_BF16)
                            ((unsigned short*)Cp)[(size_t)row * N + col] = f2bf(acc[i][j][g * 4 + rr]);
                        else
                            ((float*)Cp)[(size_t)row * N + col] = acc[i][j][g * 4 + rr];
                    }
            }
        }
}

// ---------------------------------------------------------------------------
// Sliding-window attention: Round-0 structure (single-buffered K/V staging,
// 25.2 KB LDS -> 6 blk/CU) + interior-tile fast path (numerics-identical:
// for q0b-192 <= kb < q0b every (q,key) pair provably has 0 <= dist < 256,
// so the dist/compare/select VALU work is skipped on 3 of 5 K-tiles).
// ---------------------------------------------------------------------------
__global__ __launch_bounds__(256)
void attn_kernel(const unsigned short* __restrict__ qkv,
                 const unsigned short* __restrict__ vt,
                 unsigned short* __restrict__ y)
{
    __shared__ unsigned short Ks[64 * 64];      // [key][d] swizzled
    __shared__ unsigned short Vs[64 * 64];      // [d][key] swizzled
    __shared__ unsigned short Ps[4][16 * 72];   // per-wave P strip

    const int tid  = threadIdx.x;
    const int lane = tid & 63;
    const int wave = tid >> 6;
    const int l16  = lane & 15;
    const int quad = lane >> 4;
    const int sw   = l16 & 7;                   // fragment swizzle key

    // XCD-aware decode of flat 1024-block grid
    const int g  = blockIdx.x;
    const int yq = g >> 3;
    const int hb = (g & 7) + 8 * (yq >> 5);
    const int qt = yq & 31;
    const int h  = hb & 15;
    const int b  = hb >> 4;

    const int q0b = qt * 64;            // block q-tile base
    const int q0w = q0b + wave * 16;    // this wave's q-base
    const size_t base = (size_t)b * T_;
    const int ROW  = 3 * C_;
    const int qoff = h * HS_;
    const int koff = C_ + h * HS_;
    const size_t vbase = ((size_t)(b * NH_ + h) * 64) * T_;
    unsigned short* Pstrip = Ps[wave];
    const float SC = 0.125f * 1.44269504f;

    // DMA lane mapping: lane = 8*ri + pg ; global granule gg = pg ^ ri
    const int ri = lane >> 3;
    const int gg = (lane & 7) ^ ri;

    // Q a-frags (once)
    short8 aq[2];
    #pragma unroll
    for (int ks = 0; ks < 2; ks++)
        aq[ks] = *(const short8*)&qkv[(base + q0w + l16) * ROW + qoff + ks * 32 + quad * 8];

    floatx4 O[4];
    #pragma unroll
    for (int j = 0; j < 4; j++) O[j] = (floatx4){0.f, 0.f, 0.f, 0.f};
    float psum[4] = {0.f, 0.f, 0.f, 0.f};

    int kb_lo = q0b - (WIN_ - 1);
    kb_lo = (kb_lo > 0 ? kb_lo : 0) & ~63;

    for (int kb = kb_lo; kb <= q0b; kb += 64) {
        __syncthreads();   // all waves done reading previous tile
        // stage K tile: rows wave*16 + c*8 + ri, 128 B each (coalesced)
        #pragma unroll
        for (int c = 0; c < 2; c++) {
            int row = wave * 16 + c * 8;
            async16(&qkv[(base + kb + row + ri) * ROW + koff + gg * 8],
                    &Ks[row * 64]);
            async16(&vt[vbase + (size_t)(row + ri) * T_ + kb + gg * 8],
                    &Vs[row * 64]);
        }
        __syncthreads();   // vmcnt drain -> tiles ready

        // ---- S = Q K^T ----
        floatx4 s[4];
        #pragma unroll
        for (int nt = 0; nt < 4; nt++) s[nt] = (floatx4){0.f, 0.f, 0.f, 0.f};
        #pragma unroll
        for (int ks = 0; ks < 2; ks++)
            #pragma unroll
            for (int nt = 0; nt < 4; nt++) {
                short8 bk = *(const short8*)&Ks[(nt * 16 + l16) * 64
                                                + (((ks * 4 + quad) ^ sw) * 8)];
                s[nt] = mfma16(aq[ks], bk, s[nt]);
            }

        // ---- mask + exp + psum ----
        if (kb != q0b && kb >= q0b - 192) {
            // interior tile: 0 <= dist < WIN provably true for all 16x64 pairs
            #pragma unroll
            for (int nt = 0; nt < 4; nt++)
                #pragma unroll
                for (int r = 0; r < 4; r++) {
                    float e = exp2f(s[nt][r] * SC);
                    psum[r] += e;
                    s[nt][r] = e;
                }
        } else {
            #pragma unroll
            for (int nt = 0; nt < 4; nt++)
                #pragma unroll
                for (int r = 0; r < 4; r++) {
                    int dist = (q0w + quad * 4 + r) - (kb + nt * 16 + l16);
                    float sv = ((unsigned)dist < (unsigned)WIN_) ? s[nt][r] * SC : -1e30f;
                    float e = exp2f(sv);
                    psum[r] += e;
                    s[nt][r] = e;
                }
        }

        // ---- P roundtrip (wave-private) ----
        #pragma unroll
        for (int nt = 0; nt < 4; nt++)
            #pragma unroll
            for (int r = 0; r < 4; r++)
                Pstrip[(quad * 4 + r) * 72 + nt * 16 + l16] = f2bf(s[nt][r]);

        // ---- O += P @ V ----
        #pragma unroll
        for (int ks = 0; ks < 2; ks++) {
            short8 ap = *(const short8*)&Pstrip[l16 * 72 + ks * 32 + quad * 8];
            #pragma unroll
            for (int jt = 0; jt < 4; jt++) {
                short8 bv = *(const short8*)&Vs[(jt * 16 + l16) * 64
                                                + (((ks * 4 + quad) ^ sw) * 8)];
                O[jt] = mfma16(ap, bv, O[jt]);
            }
        }
    }

    // ---- row-sum reduce ----
    #pragma unroll
    for (int r = 0; r < 4; r++) {
        #pragma unroll
        for (int off = 8; off >= 1; off >>= 1)
            psum[r] += __shfl_xor(psum[r], off, 64);
    }

    // ---- epilogue via per-wave strip, coalesced ushort8 writes ----
    #pragma unroll
    for (int jt = 0; jt < 4; jt++)
        #pragma unroll
        for (int r = 0; r < 4; r++)
            Pstrip[(quad * 4 + r) * 72 + jt * 16 + l16] = f2bf(O[jt][r] / psum[r]);
    #pragma unroll
    for (int it = 0; it < 2; it++) {
        int c = lane + 64 * it;
        int qr = c >> 3, dc = (c & 7) * 8;
        *(ushortx8*)&y[(base + q0w + qr) * C_ + qoff + dc] =
            *(const ushortx8*)&Pstrip[qr * 72 + dc];
    }
}

// ---------------------------------------------------------------------------
extern "C" void kernel_launch(void* const* d_in, const int* in_sizes, int n_in,
                              void* d_out, int out_size, void* d_ws, size_t ws_size,
                              hipStream_t stream)
{
    const float* x      = (const float*)d_in[0];
    const float* W_attn = (const float*)d_in[1];
    const float* W_proj = (const float*)d_in[2];
    float* out = (float*)d_out;

    unsigned short* xb   = (unsigned short*)d_ws;                 // [M][C]      8 MB
    unsigned short* Wa_t = xb   + (size_t)M_ * C_;                // [3C][C]     6 MB
    unsigned short* Wp_t = Wa_t + (size_t)3 * C_ * C_;            // [C][C]      2 MB
    unsigned short* qkv  = Wp_t + (size_t)C_ * C_;                // [M][3C]    24 MB (Q,K)
    unsigned short* y    = qkv  + (size_t)M_ * 3 * C_;            // [M][C]      8 MB
    unsigned short* vtg  = y    + (size_t)M_ * C_;                // [B][NH][64][T] 8 MB

    dim3 blk(256);
    prep_kernel<<<NB_CONV + NB_WA + NB_WP, blk, 0, stream>>>(x, W_attn, W_proj, xb, Wa_t, Wp_t);
    // QKV GEMM: Round-0 exact (best measured: ~45 us)
    gemm32<2, true, true><<<dim3((3 * C_) / 128, M_ / 128), blk, 0, stream>>>(
        xb, Wa_t, qkv, vtg, M_, 3 * C_, C_);
    // attn: Round-0 structure + interior fast path
    attn_kernel<<<(T_ / 64) * NH_ * B_, blk, 0, stream>>>(qkv, vtg, y);
    // proj GEMM: MT=2, single-buffered (best measured: 19.7 us, R3)
    gemm32<2, false, false><<<dim3(C_ / 128, M_ / 128), blk, 0, stream>>>(
        y, Wp_t, out, nullptr, M_, C_, C_);
}

// Round 6
// 155.568 us; speedup vs baseline: 2.1131x; 1.0291x over previous
//
#include <hip/hip_runtime.h>
#include <hip/hip_bf16.h>
#include <cstdint>

#define B_   2
#define T_   2048
#define C_   1024
#define NH_  16
#define HS_  64
#define WIN_ 256
#define M_   (B_*T_)   // 4096

typedef __attribute__((ext_vector_type(8)))  short          short8;
typedef __attribute__((ext_vector_type(8)))  unsigned short ushortx8;
typedef __attribute__((ext_vector_type(8)))  __bf16         bf16x8;
typedef __attribute__((ext_vector_type(4)))  float          floatx4;
typedef __attribute__((ext_vector_type(16))) float          floatx16;

__device__ __forceinline__ unsigned short f2bf(float f) {
    union { float f; uint32_t u; } v; v.f = f;
    uint32_t r = (v.u + 0x7FFFu + ((v.u >> 16) & 1u)) >> 16;
    return (unsigned short)r;
}

__device__ __forceinline__ floatx4 mfma16(short8 a, short8 b, floatx4 c) {
    return __builtin_amdgcn_mfma_f32_16x16x32_bf16(
        __builtin_bit_cast(bf16x8, a), __builtin_bit_cast(bf16x8, b), c, 0, 0, 0);
}
__device__ __forceinline__ floatx16 mfma32(short8 a, short8 b, floatx16 c) {
    return __builtin_amdgcn_mfma_f32_32x32x16_bf16(
        __builtin_bit_cast(bf16x8, a), __builtin_bit_cast(bf16x8, b), c, 0, 0, 0);
}

__device__ __forceinline__ void async16(const void* g, void* l) {
    __builtin_amdgcn_global_load_lds(
        (const __attribute__((address_space(1))) void*)g,
        (__attribute__((address_space(3))) void*)l, 16, 0, 0);
}

// ---------------------------------------------------------------------------
// Fused prep (x convert + both weight transposes) — Round-0 exact
// ---------------------------------------------------------------------------
#define NB_CONV 4096
#define NB_WA   768
#define NB_WP   256

__device__ void transpose_tile(const float* __restrict__ in, unsigned short* __restrict__ out,
                               int K, int N, int kt, int nt, unsigned short (*tile)[65])
{
    const int k0 = kt * 64, n0 = nt * 64;
    const int tr = threadIdx.x >> 4;
    const int tc = (threadIdx.x & 15) * 4;
    #pragma unroll
    for (int it = 0; it < 4; it++) {
        int row = tr + it * 16;
        float4 v = *(const float4*)&in[(size_t)(k0 + row) * N + n0 + tc];
        tile[row][tc + 0] = f2bf(v.x);
        tile[row][tc + 1] = f2bf(v.y);
        tile[row][tc + 2] = f2bf(v.z);
        tile[row][tc + 3] = f2bf(v.w);
    }
    __syncthreads();
    #pragma unroll
    for (int it = 0; it < 4; it++) {
        int nrow = tr + it * 16;
        ushort4 h;
        h.x = tile[tc + 0][nrow]; h.y = tile[tc + 1][nrow];
        h.z = tile[tc + 2][nrow]; h.w = tile[tc + 3][nrow];
        *(ushort4*)&out[(size_t)(n0 + nrow) * K + k0 + tc] = h;
    }
}

__global__ __launch_bounds__(256)
void prep_kernel(const float* __restrict__ x, const float* __restrict__ W_attn,
                 const float* __restrict__ W_proj,
                 unsigned short* __restrict__ xb, unsigned short* __restrict__ Wa_t,
                 unsigned short* __restrict__ Wp_t)
{
    __shared__ unsigned short tile[64][65];
    const int bid = blockIdx.x;
    if (bid < NB_CONV) {
        int i = (bid * 256 + threadIdx.x) * 4;
        float4 v = *(const float4*)&x[i];
        ushort4 h;
        h.x = f2bf(v.x); h.y = f2bf(v.y); h.z = f2bf(v.z); h.w = f2bf(v.w);
        *(ushort4*)&xb[i] = h;
    } else if (bid < NB_CONV + NB_WA) {
        int idx = bid - NB_CONV;
        transpose_tile(W_attn, Wa_t, C_, 3 * C_, idx / 48, idx % 48, tile);
    } else {
        int idx = bid - NB_CONV - NB_WA;
        transpose_tile(W_proj, Wp_t, C_, C_, idx / 16, idx % 16, tile);
    }
}

// ---------------------------------------------------------------------------
// QKV GEMM: BM=256 x BN=128, BK=64, 4 waves, per-wave output 128x64
// (acc[4][2] floatx16). Schedule, staging lane-map, and XOR-granule swizzle
// are the PROVEN R0 single-buffered pattern verbatim; only tiling changed.
// Rationale (R0-R5 counters): QKV is LDS-read-port-bound (MfmaUtil ~20%,
// HBM 18%, conflicts low). LDS reads per wave per K-tile: (Wm+Wn) granule
// rows; per-wave 128x64 drops reads:MFMA from 16:16 to 24:32 (0.75x traffic
// per FLOP). 48 KB LDS, ~190 VGPR -> 2 blocks/CU; grid 24x16=384.
// ---------------------------------------------------------------------------
__global__ __launch_bounds__(256, 2)
void gemmQKV(const unsigned short* __restrict__ A,
             const unsigned short* __restrict__ Bt,
             unsigned short* __restrict__ Cq, unsigned short* __restrict__ vt,
             int M, int N, int K)
{
    constexpr int BK = 64;
    __shared__ unsigned short As[256 * BK];   // 32 KB
    __shared__ unsigned short Bs[128 * BK];   // 16 KB

    const int tid  = threadIdx.x;
    const int lane = tid & 63;
    const int wave = tid >> 6;            // 0..3
    const int l32  = lane & 31;
    const int hi   = lane >> 5;
    const int px   = l32 & 7;
    const int wm   = (wave & 1) * 128;    // 2 waves along M
    const int wn   = (wave >> 1) * 64;    // 2 waves along N
    const int m0   = blockIdx.y * 256;
    const int n0   = blockIdx.x * 128;

    const int ri = lane >> 3;
    const int pg = lane & 7;
    const int gg = pg ^ ri;

    floatx16 acc[4][2];
    #pragma unroll
    for (int i = 0; i < 4; i++)
        #pragma unroll
        for (int j = 0; j < 2; j++) acc[i][j] = (floatx16)(0.f);

    const unsigned short* gA = &A[(size_t)(m0 + wave * 8 + ri) * K + gg * 8];
    const unsigned short* gB = &Bt[(size_t)(n0 + wave * 8 + ri) * K + gg * 8];
    unsigned short* lA = &As[(wave * 8) * BK];
    unsigned short* lB = &Bs[(wave * 8) * BK];

    for (int k0 = 0; k0 < K; k0 += BK) {
        // A: 8 slices of 32 rows (256 total); B: 4 slices (128 total)
        #pragma unroll
        for (int s = 0; s < 8; s++)
            async16(gA + k0 + (size_t)s * 32 * K, lA + s * 32 * BK);
        #pragma unroll
        for (int s = 0; s < 4; s++)
            async16(gB + k0 + (size_t)s * 32 * K, lB + s * 32 * BK);
        __syncthreads();

        #pragma unroll
        for (int ks = 0; ks < 4; ks++) {
            const int p = ((ks * 2 + hi) ^ px) * 8;
            short8 af[4], bfr[2];
            #pragma unroll
            for (int i = 0; i < 4; i++)
                af[i] = *(const short8*)(&As[(wm + i * 32 + l32) * BK + p]);
            #pragma unroll
            for (int j = 0; j < 2; j++)
                bfr[j] = *(const short8*)(&Bs[(wn + j * 32 + l32) * BK + p]);
            #pragma unroll
            for (int i = 0; i < 4; i++)
                #pragma unroll
                for (int j = 0; j < 2; j++)
                    acc[i][j] = mfma32(af[i], bfr[j], acc[i][j]);
        }
        __syncthreads();
    }

    #pragma unroll
    for (int i = 0; i < 4; i++)
        #pragma unroll
        for (int j = 0; j < 2; j++) {
            const int col  = n0 + wn + j * 32 + l32;
            const int row0 = m0 + wm + i * 32 + 4 * hi;
            if (col >= 2 * C_) {
                const int hd = col - 2 * C_;
                const int hh = hd >> 6, d = hd & 63;
                #pragma unroll
                for (int g = 0; g < 4; g++) {
                    int rowg = row0 + 8 * g;
                    int bb = rowg >> 11, t = rowg & (T_ - 1);
                    ushort4 h4;
                    h4.x = f2bf(acc[i][j][g * 4 + 0]);
                    h4.y = f2bf(acc[i][j][g * 4 + 1]);
                    h4.z = f2bf(acc[i][j][g * 4 + 2]);
                    h4.w = f2bf(acc[i][j][g * 4 + 3]);
                    *(ushort4*)&vt[((size_t)(bb * NH_ + hh) * 64 + d) * T_ + t] = h4;
                }
            } else {
                #pragma unroll
                for (int g = 0; g < 4; g++)
                    #pragma unroll
                    for (int rr = 0; rr < 4; rr++) {
                        int row = row0 + 8 * g + rr;
                        Cq[(size_t)row * N + col] = f2bf(acc[i][j][g * 4 + rr]);
                    }
            }
        }
}

// ---------------------------------------------------------------------------
// proj GEMM: Round-0 exact (MT=1, single-buffered)
// ---------------------------------------------------------------------------
template<int MT>
__global__ __launch_bounds__(256)
void gemm32(const unsigned short* __restrict__ A,
            const unsigned short* __restrict__ Bt,
            float* __restrict__ Cp, int M, int N, int K)
{
    constexpr int BK = 64;
    constexpr int BM = 64 * MT;
    __shared__ unsigned short As[BM * BK];
    __shared__ unsigned short Bs[128 * BK];

    const int tid  = threadIdx.x;
    const int lane = tid & 63;
    const int wave = tid >> 6;
    const int l32  = lane & 31;
    const int hi   = lane >> 5;
    const int px   = l32 & 7;
    const int wm   = (wave & 1) * 32 * MT;
    const int wn   = (wave >> 1) * 64;
    const int m0   = blockIdx.y * BM;
    const int n0   = blockIdx.x * 128;

    const int ri = lane >> 3;
    const int pg = lane & 7;
    const int gg = pg ^ ri;

    floatx16 acc[MT][2];
    #pragma unroll
    for (int i = 0; i < MT; i++)
        #pragma unroll
        for (int j = 0; j < 2; j++) acc[i][j] = (floatx16)(0.f);

    const unsigned short* gA = &A[(size_t)(m0 + wave * 8 + ri) * K + gg * 8];
    const unsigned short* gB = &Bt[(size_t)(n0 + wave * 8 + ri) * K + gg * 8];
    unsigned short* lA = &As[(wave * 8) * BK];
    unsigned short* lB = &Bs[(wave * 8) * BK];

    for (int k0 = 0; k0 < K; k0 += BK) {
        #pragma unroll
        for (int s = 0; s < 2 * MT; s++)
            async16(gA + k0 + (size_t)s * 32 * K, lA + s * 32 * BK);
        #pragma unroll
        for (int s = 0; s < 4; s++)
            async16(gB + k0 + (size_t)s * 32 * K, lB + s * 32 * BK);
        __syncthreads();

        #pragma unroll
        for (int ks = 0; ks < 4; ks++) {
            short8 af[MT], bfr[2];
            #pragma unroll
            for (int i = 0; i < MT; i++) {
                int r = wm + i * 32 + l32;
                int p = (ks * 2 + hi) ^ px;
                af[i] = *(const short8*)(&As[r * BK + p * 8]);
            }
            #pragma unroll
            for (int j = 0; j < 2; j++) {
                int r = wn + j * 32 + l32;
                int p = (ks * 2 + hi) ^ px;
                bfr[j] = *(const short8*)(&Bs[r * BK + p * 8]);
            }
            #pragma unroll
            for (int i = 0; i < MT; i++)
                #pragma unroll
                for (int j = 0; j < 2; j++)
                    acc[i][j] = mfma32(af[i], bfr[j], acc[i][j]);
        }
        __syncthreads();
    }

    #pragma unroll
    for (int i = 0; i < MT; i++)
        #pragma unroll
        for (int j = 0; j < 2; j++) {
            const int col  = n0 + wn + j * 32 + l32;
            const int row0 = m0 + wm + i * 32 + 4 * hi;
            #pragma unroll
            for (int g = 0; g < 4; g++)
                #pragma unroll
                for (int rr = 0; rr < 4; rr++) {
                    int row = row0 + 8 * g + rr;
                    Cp[(size_t)row * N + col] = acc[i][j][g * 4 + rr];
                }
        }
}

// ---------------------------------------------------------------------------
// Sliding-window attention: Round-0 exact (single-buffered staging, no
// fast-path branch — R5 showed the consolidated variants regressed).
// ---------------------------------------------------------------------------
__global__ __launch_bounds__(256)
void attn_kernel(const unsigned short* __restrict__ qkv,
                 const unsigned short* __restrict__ vt,
                 unsigned short* __restrict__ y)
{
    __shared__ unsigned short Ks[64 * 64];      // [key][d] swizzled
    __shared__ unsigned short Vs[64 * 64];      // [d][key] swizzled
    __shared__ unsigned short Ps[4][16 * 72];   // per-wave P strip

    const int tid  = threadIdx.x;
    const int lane = tid & 63;
    const int wave = tid >> 6;
    const int l16  = lane & 15;
    const int quad = lane >> 4;
    const int sw   = l16 & 7;                   // fragment swizzle key

    // XCD-aware decode of flat 1024-block grid
    const int g  = blockIdx.x;
    const int yq = g >> 3;
    const int hb = (g & 7) + 8 * (yq >> 5);
    const int qt = yq & 31;
    const int h  = hb & 15;
    const int b  = hb >> 4;

    const int q0b = qt * 64;            // block q-tile base
    const int q0w = q0b + wave * 16;    // this wave's q-base
    const size_t base = (size_t)b * T_;
    const int ROW  = 3 * C_;
    const int qoff = h * HS_;
    const int koff = C_ + h * HS_;
    const size_t vbase = ((size_t)(b * NH_ + h) * 64) * T_;
    unsigned short* Pstrip = Ps[wave];
    const float SC = 0.125f * 1.44269504f;

    // DMA lane mapping: lane = 8*ri + pg ; global granule gg = pg ^ ri
    const int ri = lane >> 3;
    const int gg = (lane & 7) ^ ri;

    // Q a-frags (once)
    short8 aq[2];
    #pragma unroll
    for (int ks = 0; ks < 2; ks++)
        aq[ks] = *(const short8*)&qkv[(base + q0w + l16) * ROW + qoff + ks * 32 + quad * 8];

    floatx4 O[4];
    #pragma unroll
    for (int j = 0; j < 4; j++) O[j] = (floatx4){0.f, 0.f, 0.f, 0.f};
    float psum[4] = {0.f, 0.f, 0.f, 0.f};

    int kb_lo = q0b - (WIN_ - 1);
    kb_lo = (kb_lo > 0 ? kb_lo : 0) & ~63;

    for (int kb = kb_lo; kb <= q0b; kb += 64) {
        __syncthreads();   // all waves done reading previous tile
        // stage K tile: rows wave*16 + c*8 + ri, 128 B each (coalesced)
        #pragma unroll
        for (int c = 0; c < 2; c++) {
            int row = wave * 16 + c * 8;
            async16(&qkv[(base + kb + row + ri) * ROW + koff + gg * 8],
                    &Ks[row * 64]);
            async16(&vt[vbase + (size_t)(row + ri) * T_ + kb + gg * 8],
                    &Vs[row * 64]);
        }
        __syncthreads();   // vmcnt drain -> tiles ready

        // ---- S = Q K^T ----
        floatx4 s[4];
        #pragma unroll
        for (int nt = 0; nt < 4; nt++) s[nt] = (floatx4){0.f, 0.f, 0.f, 0.f};
        #pragma unroll
        for (int ks = 0; ks < 2; ks++)
            #pragma unroll
            for (int nt = 0; nt < 4; nt++) {
                short8 bk = *(const short8*)&Ks[(nt * 16 + l16) * 64
                                                + (((ks * 4 + quad) ^ sw) * 8)];
                s[nt] = mfma16(aq[ks], bk, s[nt]);
            }

        // ---- mask + exp + psum ----
        #pragma unroll
        for (int nt = 0; nt < 4; nt++)
            #pragma unroll
            for (int r = 0; r < 4; r++) {
                int dist = (q0w + quad * 4 + r) - (kb + nt * 16 + l16);
                float sv = ((unsigned)dist < (unsigned)WIN_) ? s[nt][r] * SC : -1e30f;
                float e = exp2f(sv);
                psum[r] += e;
                s[nt][r] = e;
            }

        // ---- P roundtrip (wave-private) ----
        #pragma unroll
        for (int nt = 0; nt < 4; nt++)
            #pragma unroll
            for (int r = 0; r < 4; r++)
                Pstrip[(quad * 4 + r) * 72 + nt * 16 + l16] = f2bf(s[nt][r]);

        // ---- O += P @ V ----
        #pragma unroll
        for (int ks = 0; ks < 2; ks++) {
            short8 ap = *(const short8*)&Pstrip[l16 * 72 + ks * 32 + quad * 8];
            #pragma unroll
            for (int jt = 0; jt < 4; jt++) {
                short8 bv = *(const short8*)&Vs[(jt * 16 + l16) * 64
                                                + (((ks * 4 + quad) ^ sw) * 8)];
                O[jt] = mfma16(ap, bv, O[jt]);
            }
        }
    }

    // ---- row-sum reduce ----
    #pragma unroll
    for (int r = 0; r < 4; r++) {
        #pragma unroll
        for (int off = 8; off >= 1; off >>= 1)
            psum[r] += __shfl_xor(psum[r], off, 64);
    }

    // ---- epilogue via per-wave strip, coalesced ushort8 writes ----
    #pragma unroll
    for (int jt = 0; jt < 4; jt++)
        #pragma unroll
        for (int r = 0; r < 4; r++)
            Pstrip[(quad * 4 + r) * 72 + jt * 16 + l16] = f2bf(O[jt][r] / psum[r]);
    #pragma unroll
    for (int it = 0; it < 2; it++) {
        int c = lane + 64 * it;
        int qr = c >> 3, dc = (c & 7) * 8;
        *(ushortx8*)&y[(base + q0w + qr) * C_ + qoff + dc] =
            *(const ushortx8*)&Pstrip[qr * 72 + dc];
    }
}

// ---------------------------------------------------------------------------
extern "C" void kernel_launch(void* const* d_in, const int* in_sizes, int n_in,
                              void* d_out, int out_size, void* d_ws, size_t ws_size,
                              hipStream_t stream)
{
    const float* x      = (const float*)d_in[0];
    const float* W_attn = (const float*)d_in[1];
    const float* W_proj = (const float*)d_in[2];
    float* out = (float*)d_out;

    unsigned short* xb   = (unsigned short*)d_ws;                 // [M][C]      8 MB
    unsigned short* Wa_t = xb   + (size_t)M_ * C_;                // [3C][C]     6 MB
    unsigned short* Wp_t = Wa_t + (size_t)3 * C_ * C_;            // [C][C]      2 MB
    unsigned short* qkv  = Wp_t + (size_t)C_ * C_;                // [M][3C]    24 MB (Q,K)
    unsigned short* y    = qkv  + (size_t)M_ * 3 * C_;            // [M][C]      8 MB
    unsigned short* vtg  = y    + (size_t)M_ * C_;                // [B][NH][64][T] 8 MB

    dim3 blk(256);
    prep_kernel<<<NB_CONV + NB_WA + NB_WP, blk, 0, stream>>>(x, W_attn, W_proj, xb, Wa_t, Wp_t);
    // QKV GEMM: 256x128 tile, per-wave 128x64 (0.75x LDS bytes per FLOP)
    gemmQKV<<<dim3((3 * C_) / 128, M_ / 256), blk, 0, stream>>>(
        xb, Wa_t, qkv, vtg, M_, 3 * C_, C_);
    // attn: Round-0 exact
    attn_kernel<<<(T_ / 64) * NH_ * B_, blk, 0, stream>>>(qkv, vtg, y);
    // proj GEMM: Round-0 exact (MT=1)
    gemm32<1><<<dim3(C_ / 128, M_ / 64), blk, 0, stream>>>(
        y, Wp_t, out, M_, C_, C_);
}

// Round 7
// 150.451 us; speedup vs baseline: 2.1850x; 1.0340x over previous
//
#include <hip/hip_runtime.h>
#include <hip/hip_bf16.h>
#include <cstdint>

#define B_   2
#define T_   2048
#define C_   1024
#define NH_  16
#define HS_  64
#define WIN_ 256
#define M_   (B_*T_)   // 4096

typedef __attribute__((ext_vector_type(8)))  short          short8;
typedef __attribute__((ext_vector_type(8)))  unsigned short ushortx8;
typedef __attribute__((ext_vector_type(8)))  __bf16         bf16x8;
typedef __attribute__((ext_vector_type(4)))  float          floatx4;
typedef __attribute__((ext_vector_type(16))) float          floatx16;

__device__ __forceinline__ unsigned short f2bf(float f) {
    union { float f; uint32_t u; } v; v.f = f;
    uint32_t r = (v.u + 0x7FFFu + ((v.u >> 16) & 1u)) >> 16;
    return (unsigned short)r;
}

__device__ __forceinline__ floatx4 mfma16(short8 a, short8 b, floatx4 c) {
    return __builtin_amdgcn_mfma_f32_16x16x32_bf16(
        __builtin_bit_cast(bf16x8, a), __builtin_bit_cast(bf16x8, b), c, 0, 0, 0);
}
__device__ __forceinline__ floatx16 mfma32(short8 a, short8 b, floatx16 c) {
    return __builtin_amdgcn_mfma_f32_32x32x16_bf16(
        __builtin_bit_cast(bf16x8, a), __builtin_bit_cast(bf16x8, b), c, 0, 0, 0);
}

__device__ __forceinline__ void async16(const void* g, void* l) {
    __builtin_amdgcn_global_load_lds(
        (const __attribute__((address_space(1))) void*)g,
        (__attribute__((address_space(3))) void*)l, 16, 0, 0);
}

// ---------------------------------------------------------------------------
// Fused prep (x convert + both weight transposes) — Round-0 exact
// ---------------------------------------------------------------------------
#define NB_CONV 4096
#define NB_WA   768
#define NB_WP   256

__device__ void transpose_tile(const float* __restrict__ in, unsigned short* __restrict__ out,
                               int K, int N, int kt, int nt, unsigned short (*tile)[65])
{
    const int k0 = kt * 64, n0 = nt * 64;
    const int tr = threadIdx.x >> 4;
    const int tc = (threadIdx.x & 15) * 4;
    #pragma unroll
    for (int it = 0; it < 4; it++) {
        int row = tr + it * 16;
        float4 v = *(const float4*)&in[(size_t)(k0 + row) * N + n0 + tc];
        tile[row][tc + 0] = f2bf(v.x);
        tile[row][tc + 1] = f2bf(v.y);
        tile[row][tc + 2] = f2bf(v.z);
        tile[row][tc + 3] = f2bf(v.w);
    }
    __syncthreads();
    #pragma unroll
    for (int it = 0; it < 4; it++) {
        int nrow = tr + it * 16;
        ushort4 h;
        h.x = tile[tc + 0][nrow]; h.y = tile[tc + 1][nrow];
        h.z = tile[tc + 2][nrow]; h.w = tile[tc + 3][nrow];
        *(ushort4*)&out[(size_t)(n0 + nrow) * K + k0 + tc] = h;
    }
}

__global__ __launch_bounds__(256)
void prep_kernel(const float* __restrict__ x, const float* __restrict__ W_attn,
                 const float* __restrict__ W_proj,
                 unsigned short* __restrict__ xb, unsigned short* __restrict__ Wa_t,
                 unsigned short* __restrict__ Wp_t)
{
    __shared__ unsigned short tile[64][65];
    const int bid = blockIdx.x;
    if (bid < NB_CONV) {
        int i = (bid * 256 + threadIdx.x) * 4;
        float4 v = *(const float4*)&x[i];
        ushort4 h;
        h.x = f2bf(v.x); h.y = f2bf(v.y); h.z = f2bf(v.z); h.w = f2bf(v.w);
        *(ushort4*)&xb[i] = h;
    } else if (bid < NB_CONV + NB_WA) {
        int idx = bid - NB_CONV;
        transpose_tile(W_attn, Wa_t, C_, 3 * C_, idx / 48, idx % 48, tile);
    } else {
        int idx = bid - NB_CONV - NB_WA;
        transpose_tile(W_proj, Wp_t, C_, C_, idx / 16, idx % 16, tile);
    }
}

// ---------------------------------------------------------------------------
// QKV GEMM: Round-0 exact. 128x128 tile, MT=2, 4 waves, per-wave 64x64,
// single-buffered, XOR-granule swizzle. This design point is at its resource
// cap (VGPR+AGPR ~164 -> 3 waves/SIMD -> 3 blk/CU = grid average): R6 showed
// fatter per-wave tiles lose occupancy; R4 showed dbuf/counted-vmcnt is null.
// Measured ~45 us (573 TF).
// ---------------------------------------------------------------------------
template<int MT, bool OUT_BF16, bool VSPLIT>
__global__ __launch_bounds__(256)
void gemm32(const unsigned short* __restrict__ A,
            const unsigned short* __restrict__ Bt,
            void* __restrict__ Cp, unsigned short* __restrict__ vt,
            int M, int N, int K)
{
    constexpr int BK = 64;
    constexpr int BM = 64 * MT;
    __shared__ unsigned short As[BM * BK];
    __shared__ unsigned short Bs[128 * BK];

    const int tid  = threadIdx.x;
    const int lane = tid & 63;
    const int wave = tid >> 6;
    const int l32  = lane & 31;
    const int hi   = lane >> 5;
    const int px   = l32 & 7;
    const int wm   = (wave & 1) * 32 * MT;
    const int wn   = (wave >> 1) * 64;
    const int m0   = blockIdx.y * BM;
    const int n0   = blockIdx.x * 128;

    const int ri = lane >> 3;
    const int pg = lane & 7;
    const int gg = pg ^ ri;

    floatx16 acc[MT][2];
    #pragma unroll
    for (int i = 0; i < MT; i++)
        #pragma unroll
        for (int j = 0; j < 2; j++) acc[i][j] = (floatx16)(0.f);

    const unsigned short* gA = &A[(size_t)(m0 + wave * 8 + ri) * K + gg * 8];
    const unsigned short* gB = &Bt[(size_t)(n0 + wave * 8 + ri) * K + gg * 8];
    unsigned short* lA = &As[(wave * 8) * BK];
    unsigned short* lB = &Bs[(wave * 8) * BK];

    for (int k0 = 0; k0 < K; k0 += BK) {
        #pragma unroll
        for (int s = 0; s < 2 * MT; s++)
            async16(gA + k0 + (size_t)s * 32 * K, lA + s * 32 * BK);
        #pragma unroll
        for (int s = 0; s < 4; s++)
            async16(gB + k0 + (size_t)s * 32 * K, lB + s * 32 * BK);
        __syncthreads();

        #pragma unroll
        for (int ks = 0; ks < 4; ks++) {
            short8 af[MT], bfr[2];
            #pragma unroll
            for (int i = 0; i < MT; i++) {
                int r = wm + i * 32 + l32;
                int p = (ks * 2 + hi) ^ px;
                af[i] = *(const short8*)(&As[r * BK + p * 8]);
            }
            #pragma unroll
            for (int j = 0; j < 2; j++) {
                int r = wn + j * 32 + l32;
                int p = (ks * 2 + hi) ^ px;
                bfr[j] = *(const short8*)(&Bs[r * BK + p * 8]);
            }
            #pragma unroll
            for (int i = 0; i < MT; i++)
                #pragma unroll
                for (int j = 0; j < 2; j++)
                    acc[i][j] = mfma32(af[i], bfr[j], acc[i][j]);
        }
        __syncthreads();
    }

    #pragma unroll
    for (int i = 0; i < MT; i++)
        #pragma unroll
        for (int j = 0; j < 2; j++) {
            const int col  = n0 + wn + j * 32 + l32;
            const int row0 = m0 + wm + i * 32 + 4 * hi;
            if (VSPLIT && col >= 2 * C_) {
                const int hd = col - 2 * C_;
                const int hh = hd >> 6, d = hd & 63;
                #pragma unroll
                for (int g = 0; g < 4; g++) {
                    int rowg = row0 + 8 * g;
                    int bb = rowg >> 11, t = rowg & (T_ - 1);
                    ushort4 h4;
                    h4.x = f2bf(acc[i][j][g * 4 + 0]);
                    h4.y = f2bf(acc[i][j][g * 4 + 1]);
                    h4.z = f2bf(acc[i][j][g * 4 + 2]);
                    h4.w = f2bf(acc[i][j][g * 4 + 3]);
                    *(ushort4*)&vt[((size_t)(bb * NH_ + hh) * 64 + d) * T_ + t] = h4;
                }
            } else {
                #pragma unroll
                for (int g = 0; g < 4; g++)
                    #pragma unroll
                    for (int rr = 0; rr < 4; rr++) {
                        int row = row0 + 8 * g + rr;
                        if (OUT_BF16)
                            ((unsigned short*)Cp)[(size_t)row * N + col] = f2bf(acc[i][j][g * 4 + rr]);
                        else
                            ((float*)Cp)[(size_t)row * N + col] = acc[i][j][g * 4 + rr];
                    }
            }
        }
}

// ---------------------------------------------------------------------------
// proj GEMM: 64x64 tile, 4 waves (2x2), per-wave 32x32, grid (16,64)=1024
// -> 4 blocks/CU, 16 waves/CU (vs MT=1/BN=128's 2 blk / 8 waves). Theory:
// proj is grid/TLP-limited cold (R3-R5: fatter tiles regressed); doubling
// independent barrier groups doubles the stage-drain cover (m114 mechanism).
// Same proven staging lane-map + XOR-granule swizzle; 16 KB LDS.
// ---------------------------------------------------------------------------
__global__ __launch_bounds__(256)
void gemmP(const unsigned short* __restrict__ A,
           const unsigned short* __restrict__ Bt,
           float* __restrict__ Cp, int M, int N, int K)
{
    constexpr int BK = 64;
    __shared__ unsigned short As[64 * BK];   // 8 KB
    __shared__ unsigned short Bs[64 * BK];   // 8 KB

    const int tid  = threadIdx.x;
    const int lane = tid & 63;
    const int wave = tid >> 6;            // 0..3
    const int l32  = lane & 31;
    const int hi   = lane >> 5;
    const int px   = l32 & 7;
    const int wm   = (wave & 1) * 32;     // 2 waves along M
    const int wn   = (wave >> 1) * 32;    // 2 waves along N
    const int m0   = blockIdx.y * 64;
    const int n0   = blockIdx.x * 64;

    const int ri = lane >> 3;
    const int pg = lane & 7;
    const int gg = pg ^ ri;

    floatx16 acc = (floatx16)(0.f);

    const unsigned short* gA = &A[(size_t)(m0 + wave * 8 + ri) * K + gg * 8];
    const unsigned short* gB = &Bt[(size_t)(n0 + wave * 8 + ri) * K + gg * 8];
    unsigned short* lA = &As[(wave * 8) * BK];
    unsigned short* lB = &Bs[(wave * 8) * BK];

    for (int k0 = 0; k0 < K; k0 += BK) {
        // A: 2 slices of 32 rows (64 total); B: same
        #pragma unroll
        for (int s = 0; s < 2; s++)
            async16(gA + k0 + (size_t)s * 32 * K, lA + s * 32 * BK);
        #pragma unroll
        for (int s = 0; s < 2; s++)
            async16(gB + k0 + (size_t)s * 32 * K, lB + s * 32 * BK);
        __syncthreads();

        #pragma unroll
        for (int ks = 0; ks < 4; ks++) {
            const int p = ((ks * 2 + hi) ^ px) * 8;
            short8 af = *(const short8*)(&As[(wm + l32) * BK + p]);
            short8 bf = *(const short8*)(&Bs[(wn + l32) * BK + p]);
            acc = mfma32(af, bf, acc);
        }
        __syncthreads();
    }

    const int col  = n0 + wn + l32;
    const int row0 = m0 + wm + 4 * hi;
    #pragma unroll
    for (int g = 0; g < 4; g++)
        #pragma unroll
        for (int rr = 0; rr < 4; rr++) {
            int row = row0 + 8 * g + rr;
            Cp[(size_t)row * N + col] = acc[g * 4 + rr];
        }
}

// ---------------------------------------------------------------------------
// Sliding-window attention: Round-0 exact.
// ---------------------------------------------------------------------------
__global__ __launch_bounds__(256)
void attn_kernel(const unsigned short* __restrict__ qkv,
                 const unsigned short* __restrict__ vt,
                 unsigned short* __restrict__ y)
{
    __shared__ unsigned short Ks[64 * 64];      // [key][d] swizzled
    __shared__ unsigned short Vs[64 * 64];      // [d][key] swizzled
    __shared__ unsigned short Ps[4][16 * 72];   // per-wave P strip

    const int tid  = threadIdx.x;
    const int lane = tid & 63;
    const int wave = tid >> 6;
    const int l16  = lane & 15;
    const int quad = lane >> 4;
    const int sw   = l16 & 7;                   // fragment swizzle key

    // XCD-aware decode of flat 1024-block grid
    const int g  = blockIdx.x;
    const int yq = g >> 3;
    const int hb = (g & 7) + 8 * (yq >> 5);
    const int qt = yq & 31;
    const int h  = hb & 15;
    const int b  = hb >> 4;

    const int q0b = qt * 64;            // block q-tile base
    const int q0w = q0b + wave * 16;    // this wave's q-base
    const size_t base = (size_t)b * T_;
    const int ROW  = 3 * C_;
    const int qoff = h * HS_;
    const int koff = C_ + h * HS_;
    const size_t vbase = ((size_t)(b * NH_ + h) * 64) * T_;
    unsigned short* Pstrip = Ps[wave];
    const float SC = 0.125f * 1.44269504f;

    // DMA lane mapping: lane = 8*ri + pg ; global granule gg = pg ^ ri
    const int ri = lane >> 3;
    const int gg = (lane & 7) ^ ri;

    // Q a-frags (once)
    short8 aq[2];
    #pragma unroll
    for (int ks = 0; ks < 2; ks++)
        aq[ks] = *(const short8*)&qkv[(base + q0w + l16) * ROW + qoff + ks * 32 + quad * 8];

    floatx4 O[4];
    #pragma unroll
    for (int j = 0; j < 4; j++) O[j] = (floatx4){0.f, 0.f, 0.f, 0.f};
    float psum[4] = {0.f, 0.f, 0.f, 0.f};

    int kb_lo = q0b - (WIN_ - 1);
    kb_lo = (kb_lo > 0 ? kb_lo : 0) & ~63;

    for (int kb = kb_lo; kb <= q0b; kb += 64) {
        __syncthreads();   // all waves done reading previous tile
        // stage K tile: rows wave*16 + c*8 + ri, 128 B each (coalesced)
        #pragma unroll
        for (int c = 0; c < 2; c++) {
            int row = wave * 16 + c * 8;
            async16(&qkv[(base + kb + row + ri) * ROW + koff + gg * 8],
                    &Ks[row * 64]);
            async16(&vt[vbase + (size_t)(row + ri) * T_ + kb + gg * 8],
                    &Vs[row * 64]);
        }
        __syncthreads();   // vmcnt drain -> tiles ready

        // ---- S = Q K^T ----
        floatx4 s[4];
        #pragma unroll
        for (int nt = 0; nt < 4; nt++) s[nt] = (floatx4){0.f, 0.f, 0.f, 0.f};
        #pragma unroll
        for (int ks = 0; ks < 2; ks++)
            #pragma unroll
            for (int nt = 0; nt < 4; nt++) {
                short8 bk = *(const short8*)&Ks[(nt * 16 + l16) * 64
                                                + (((ks * 4 + quad) ^ sw) * 8)];
                s[nt] = mfma16(aq[ks], bk, s[nt]);
            }

        // ---- mask + exp + psum ----
        #pragma unroll
        for (int nt = 0; nt < 4; nt++)
            #pragma unroll
            for (int r = 0; r < 4; r++) {
                int dist = (q0w + quad * 4 + r) - (kb + nt * 16 + l16);
                float sv = ((unsigned)dist < (unsigned)WIN_) ? s[nt][r] * SC : -1e30f;
                float e = exp2f(sv);
                psum[r] += e;
                s[nt][r] = e;
            }

        // ---- P roundtrip (wave-private) ----
        #pragma unroll
        for (int nt = 0; nt < 4; nt++)
            #pragma unroll
            for (int r = 0; r < 4; r++)
                Pstrip[(quad * 4 + r) * 72 + nt * 16 + l16] = f2bf(s[nt][r]);

        // ---- O += P @ V ----
        #pragma unroll
        for (int ks = 0; ks < 2; ks++) {
            short8 ap = *(const short8*)&Pstrip[l16 * 72 + ks * 32 + quad * 8];
            #pragma unroll
            for (int jt = 0; jt < 4; jt++) {
                short8 bv = *(const short8*)&Vs[(jt * 16 + l16) * 64
                                                + (((ks * 4 + quad) ^ sw) * 8)];
                O[jt] = mfma16(ap, bv, O[jt]);
            }
        }
    }

    // ---- row-sum reduce ----
    #pragma unroll
    for (int r = 0; r < 4; r++) {
        #pragma unroll
        for (int off = 8; off >= 1; off >>= 1)
            psum[r] += __shfl_xor(psum[r], off, 64);
    }

    // ---- epilogue via per-wave strip, coalesced ushort8 writes ----
    #pragma unroll
    for (int jt = 0; jt < 4; jt++)
        #pragma unroll
        for (int r = 0; r < 4; r++)
            Pstrip[(quad * 4 + r) * 72 + jt * 16 + l16] = f2bf(O[jt][r] / psum[r]);
    #pragma unroll
    for (int it = 0; it < 2; it++) {
        int c = lane + 64 * it;
        int qr = c >> 3, dc = (c & 7) * 8;
        *(ushortx8*)&y[(base + q0w + qr) * C_ + qoff + dc] =
            *(const ushortx8*)&Pstrip[qr * 72 + dc];
    }
}

// ---------------------------------------------------------------------------
extern "C" void kernel_launch(void* const* d_in, const int* in_sizes, int n_in,
                              void* d_out, int out_size, void* d_ws, size_t ws_size,
                              hipStream_t stream)
{
    const float* x      = (const float*)d_in[0];
    const float* W_attn = (const float*)d_in[1];
    const float* W_proj = (const float*)d_in[2];
    float* out = (float*)d_out;

    unsigned short* xb   = (unsigned short*)d_ws;                 // [M][C]      8 MB
    unsigned short* Wa_t = xb   + (size_t)M_ * C_;                // [3C][C]     6 MB
    unsigned short* Wp_t = Wa_t + (size_t)3 * C_ * C_;            // [C][C]      2 MB
    unsigned short* qkv  = Wp_t + (size_t)C_ * C_;                // [M][3C]    24 MB (Q,K)
    unsigned short* y    = qkv  + (size_t)M_ * 3 * C_;            // [M][C]      8 MB
    unsigned short* vtg  = y    + (size_t)M_ * C_;                // [B][NH][64][T] 8 MB

    dim3 blk(256);
    prep_kernel<<<NB_CONV + NB_WA + NB_WP, blk, 0, stream>>>(x, W_attn, W_proj, xb, Wa_t, Wp_t);
    // QKV GEMM: Round-0 exact
    gemm32<2, true, true><<<dim3((3 * C_) / 128, M_ / 128), blk, 0, stream>>>(
        xb, Wa_t, qkv, vtg, M_, 3 * C_, C_);
    // attn: Round-0 exact
    attn_kernel<<<(T_ / 64) * NH_ * B_, blk, 0, stream>>>(qkv, vtg, y);
    // proj GEMM: 64x64 tile, grid 1024 -> 4 blk/CU (TLP-limited theory)
    gemmP<<<dim3(C_ / 64, M_ / 64), blk, 0, stream>>>(
        y, Wp_t, out, M_, C_, C_);
}